// Round 13
// baseline (185.310 us; speedup 1.0000x reference)
//
#include <hip/hip_runtime.h>
#include <hip/hip_bf16.h>

#define NN 51200
#define EE 819200
#define BB 64
#define NS 32
#define R4 4
#define RSIZE 12800   // NN / R4
#define NBUCK 512     // dst-range buckets
#define NPB 100       // nodes per bucket
#define CAP 4096      // bucket capacity (mean 1600, 60 sigma)
#define EPB 4096      // edges per block in bucketA

typedef __attribute__((ext_vector_type(8))) short short8;
typedef __attribute__((ext_vector_type(4))) float f32x4;

__device__ __forceinline__ ushort f2bf(float f) {
    unsigned int u = __float_as_uint(f);
    unsigned int r = (u + 0x7FFFu + ((u >> 16) & 1u)) >> 16;
    return (ushort)r;
}
__device__ __forceinline__ unsigned int cvt_pk_bf16(float lo, float hi) {
    unsigned int r;
    asm("v_cvt_pk_bf16_f32 %0, %1, %2" : "=v"(r) : "v"(lo), "v"(hi));
    return r;
}
__device__ __forceinline__ float blo(unsigned int q) { return __uint_as_float(q << 16); }
__device__ __forceinline__ float bhi(unsigned int q) { return __uint_as_float(q & 0xFFFF0000u); }

// ---------------- weight prep ----------------
__global__ void prep_weights(const float* __restrict__ gW1, const float* __restrict__ lW1,
                             ushort* __restrict__ W1p, ushort* __restrict__ L1p) {
    int tid = threadIdx.x;
    for (int idx = tid; idx < 64 * 256; idx += 512) {
        int i = idx & 7, c = (idx >> 3) & 255, q = idx >> 11;
        int k = (q >> 2) * 32 + (q & 3) * 8 + i;
        W1p[idx] = f2bf(c < 128 ? gW1[k * 128 + c] : gW1[(64 + k) * 128 + (c - 128)]);
        L1p[idx] = f2bf(c < 128 ? lW1[k * 128 + c] : lW1[(128 + k) * 128 + (c - 128)]);
    }
}

// ---------------- CSR build ----------------
// bucketA: bin pairs by dst-bucket into btmp chunks; accumulate per-(range,bucket) counts
__global__ __launch_bounds__(512) void bucketA_kernel(const int* __restrict__ eidx,
                                                      int* __restrict__ bcnt,
                                                      int* __restrict__ cnt4,
                                                      int2* __restrict__ btmp) {
    __shared__ int2 sp[EPB];                      // 32 KB
    __shared__ ushort perm[EPB];                  //  8 KB
    __shared__ int cnts[NBUCK], lofs[NBUCK], lcur[NBUCK];  // 6 KB
    __shared__ int c4[R4 * NBUCK];                //  8 KB
    const int tid = threadIdx.x;
    const int base = blockIdx.x * EPB;

    cnts[tid] = 0;
#pragma unroll
    for (int j = 0; j < 4; ++j) c4[tid + j * 512] = 0;
    __syncthreads();
    for (int i = tid; i < EPB; i += 512) {
        int d = eidx[EE + base + i], s = eidx[base + i];
        sp[i] = make_int2(s, d);
        atomicAdd(&cnts[d / NPB], 1);
        atomicAdd(&c4[(s / RSIZE) * NBUCK + d / NPB], 1);
    }
    __syncthreads();
    for (int j = tid; j < R4 * NBUCK; j += 512)
        if (c4[j]) atomicAdd(&cnt4[j], c4[j]);
    const int v = cnts[tid];
    lofs[tid] = v;
    __syncthreads();
    for (int o = 1; o < NBUCK; o <<= 1) {
        int u = (tid >= o) ? lofs[tid - o] : 0;
        __syncthreads();
        lofs[tid] += u;
        __syncthreads();
    }
    const int excl = lofs[tid] - v;
    lofs[tid] = excl;
    lcur[tid] = excl;
    const int mygbase = (v > 0) ? atomicAdd(&bcnt[tid * 16], v) : 0;
    __syncthreads();
    for (int i = tid; i < EPB; i += 512) {
        int pos = atomicAdd(&lcur[sp[i].y / NPB], 1);
        perm[pos] = (ushort)i;
    }
    __syncthreads();
    {
        const int c = cnts[tid];
        const int lo = lofs[tid];
        int2* dst = btmp + (long)tid * CAP + mygbase;
        for (int j = 0; j < c; ++j) dst[j] = sp[perm[lo + j]];
    }
}

// scan 2048 (range-major, bucket-minor) counts -> base4; set roffs4 sentinel
__global__ __launch_bounds__(512) void scan2048_kernel(const int* __restrict__ cnt4,
                                                       int* __restrict__ base4,
                                                       int* __restrict__ roffs4) {
    __shared__ int s[512];
    const int t = threadIdx.x;
    int v0 = cnt4[t * 4], v1 = cnt4[t * 4 + 1], v2 = cnt4[t * 4 + 2], v3 = cnt4[t * 4 + 3];
    int sum = v0 + v1 + v2 + v3;
    s[t] = sum;
    __syncthreads();
    for (int o = 1; o < 512; o <<= 1) {
        int u = (t >= o) ? s[t - o] : 0;
        __syncthreads();
        s[t] += u;
        __syncthreads();
    }
    int run = s[t] - sum;
    base4[t * 4] = run;
    base4[t * 4 + 1] = run + v0;
    base4[t * 4 + 2] = run + v0 + v1;
    base4[t * 4 + 3] = run + v0 + v1 + v2;
    if (t == 0) roffs4[R4 * NN] = EE;
}

// bucketB: per dst-bucket, counting-sort by (range, node); emit roffs4 + packed csr
__global__ __launch_bounds__(256) void bucketB_kernel(const int2* __restrict__ btmp,
                                                      const int* __restrict__ bcnt,
                                                      const int* __restrict__ base4,
                                                      int* __restrict__ roffs4,
                                                      int* __restrict__ csr) {
    __shared__ int lcnt[R4 * NPB];
    __shared__ int lcur[R4 * NPB];
    __shared__ int2 pairs[2048];
    const int bkt = blockIdx.x, tid = threadIdx.x;
    const int cnt = bcnt[bkt * 16];
    for (int j = tid; j < R4 * NPB; j += 256) lcnt[j] = 0;
    __syncthreads();
    for (int i = tid; i < cnt; i += 256) {
        int2 p = btmp[(long)bkt * CAP + i];
        if (i < 2048) pairs[i] = p;
        int key = (p.x / RSIZE) * NPB + (p.y - bkt * NPB);
        atomicAdd(&lcnt[key], 1);
    }
    __syncthreads();
    if (tid < R4) {   // per-range serial prefix over this bucket's 100 node-cells
        int run = base4[tid * NBUCK + bkt];
        for (int nl = 0; nl < NPB; ++nl) {
            roffs4[tid * NN + bkt * NPB + nl] = run;
            lcur[tid * NPB + nl] = run;
            run += lcnt[tid * NPB + nl];
        }
    }
    __syncthreads();
    for (int i = tid; i < cnt; i += 256) {
        int2 p = (i < 2048) ? pairs[i] : btmp[(long)bkt * CAP + i];
        int key = (p.x / RSIZE) * NPB + (p.y - bkt * NPB);
        int pos = atomicAdd(&lcur[key], 1);
        csr[pos] = p.x | ((p.y & 15) << 17);   // src (17b) | node-delta (4b)
    }
}

// ---------------- node-table GEMM ----------------
__global__ __launch_bounds__(512) void pq_gemm(
        const float* __restrict__ x, const ushort* __restrict__ Wp,
        const float* __restrict__ bias1, const float* __restrict__ T12,
        const int* __restrict__ batch, ushort* __restrict__ out) {
    const int tid = threadIdx.x;
    const int w = tid >> 6, l = tid & 63, lr = l & 15, lg = l >> 4;
    const int node = blockIdx.x * 128 + w * 16 + lr;

    short8 xa[2];
#pragma unroll
    for (int ks = 0; ks < 2; ++ks) {
        const float4* bp = reinterpret_cast<const float4*>(x + (long)node * 64 + ks * 32 + lg * 8);
        float4 f0 = bp[0], f1 = bp[1];
        union { short8 s; unsigned int u[4]; } t;
        t.u[0] = cvt_pk_bf16(f0.x, f0.y);
        t.u[1] = cvt_pk_bf16(f0.z, f0.w);
        t.u[2] = cvt_pk_bf16(f1.x, f1.y);
        t.u[3] = cvt_pk_bf16(f1.z, f1.w);
        xa[ks] = t.s;
    }
    f32x4 acc[16];
#pragma unroll
    for (int t = 0; t < 16; ++t)
#pragma unroll
        for (int i = 0; i < 4; ++i)
            acc[t][i] = (t < 8) ? bias1[t * 16 + lg * 4 + i] : 0.f;
#pragma unroll
    for (int ks = 0; ks < 2; ++ks)
#pragma unroll
        for (int t = 0; t < 16; ++t) {
            short8 wf = *reinterpret_cast<const short8*>(Wp + (((ks * 4 + lg) * 256) + t * 16 + lr) * 8);
            acc[t] = __builtin_amdgcn_mfma_f32_16x16x32_bf16(wf, xa[ks], acc[t], 0, 0, 0);
        }
    if (T12) {
        const float* tp = T12 + (long)batch[node] * 256;
#pragma unroll
        for (int t = 0; t < 16; ++t)
#pragma unroll
            for (int i = 0; i < 4; ++i)
                acc[t][i] += tp[t * 16 + lg * 4 + i];
    }
#pragma unroll
    for (int t = 0; t < 16; ++t) {
        uint2 v;
        v.x = cvt_pk_bf16(acc[t][0], acc[t][1]);
        v.y = cvt_pk_bf16(acc[t][2], acc[t][3]);
        *reinterpret_cast<uint2*>(out + (long)node * 256 + t * 16 + lg * 4) = v;
    }
}

// ---------------- global edge pass: src-range partitioned, XCD-pinned ----------------
// block = (64-node group g, range rr); rr = (blockIdx&7)>>1 -> XCD-pinned Q working set 3.3MB
__global__ __launch_bounds__(256) void global_edge(
        const ushort* __restrict__ PQ, const int* __restrict__ csr,
        const int* __restrict__ roffs4, const float* __restrict__ e,
        const int* __restrict__ batch,
        float* __restrict__ hidpart, float* __restrict__ esumpart) {
    const int tid = threadIdx.x, w = tid >> 6, l = tid & 63;
    const int rr = (blockIdx.x & 7) >> 1;
    const int g  = (blockIdx.x >> 3) * 2 + (blockIdx.x & 1);
    const int n0 = __builtin_amdgcn_readfirstlane(g * 64 + w * 16);
    const int slot = (blockIdx.x * 4 + w) & (NS - 1);

    int i = roffs4[rr * NN + n0];
    const int iend = roffs4[rr * NN + n0 + 16];

    float accp0 = 0.f, accp1 = 0.f, eacc = 0.f;
    float p0 = 0.f, p1 = 0.f, ev = 0.f;
    int curD = -1, curb = batch[n0];

    for (; i + 8 <= iend; i += 8) {
        int vv[8]; unsigned int qv[8];
#pragma unroll
        for (int k = 0; k < 8; ++k) vv[k] = csr[i + k];        // scalar (uniform addr)
#pragma unroll
        for (int k = 0; k < 8; ++k) {
            const int s = vv[k] & 0x1FFFF;
            qv[k] = *reinterpret_cast<const unsigned int*>(PQ + (long)s * 256 + 128 + 2 * l);
        }
#pragma unroll
        for (int k = 0; k < 8; ++k) {
            const int D = vv[k] >> 17;
            if (D != curD) {                    // uniform branch; D monotone
                const int node = n0 + D;
                const int bb = batch[node];
                if (bb != curb) {
                    float* hp = hidpart + (long)slot * (BB * 128) + curb * 128;
                    atomicAdd(hp + 2 * l, accp0);
                    atomicAdd(hp + 2 * l + 1, accp1);
                    if (l == 0) atomicAdd(&esumpart[slot * BB + curb], eacc);
                    accp0 = accp1 = eacc = 0.f;
                    curb = bb;
                }
                const unsigned int pdu = *reinterpret_cast<const unsigned int*>(PQ + (long)node * 256 + 2 * l);
                p0 = blo(pdu); p1 = bhi(pdu);
                ev = e[node];
                curD = D;
            }
            accp0 += ev * fmaxf(p0 + blo(qv[k]), 0.f);
            accp1 += ev * fmaxf(p1 + bhi(qv[k]), 0.f);
            eacc += ev;
        }
    }
    for (; i < iend; ++i) {     // tail
        const int v = csr[i];
        const int s = v & 0x1FFFF;
        const unsigned int q = *reinterpret_cast<const unsigned int*>(PQ + (long)s * 256 + 128 + 2 * l);
        const int D = v >> 17;
        if (D != curD) {
            const int node = n0 + D;
            const int bb = batch[node];
            if (bb != curb) {
                float* hp = hidpart + (long)slot * (BB * 128) + curb * 128;
                atomicAdd(hp + 2 * l, accp0);
                atomicAdd(hp + 2 * l + 1, accp1);
                if (l == 0) atomicAdd(&esumpart[slot * BB + curb], eacc);
                accp0 = accp1 = eacc = 0.f;
                curb = bb;
            }
            const unsigned int pdu = *reinterpret_cast<const unsigned int*>(PQ + (long)node * 256 + 2 * l);
            p0 = blo(pdu); p1 = bhi(pdu);
            ev = e[node];
            curD = D;
        }
        accp0 += ev * fmaxf(p0 + blo(q), 0.f);
        accp1 += ev * fmaxf(p1 + bhi(q), 0.f);
        eacc += ev;
    }
    {   // final flush
        float* hp = hidpart + (long)slot * (BB * 128) + curb * 128;
        atomicAdd(hp + 2 * l, accp0);
        atomicAdd(hp + 2 * l + 1, accp1);
        if (l == 0) atomicAdd(&esumpart[slot * BB + curb], eacc);
    }
}

// ---------------- fused: hidsum reduce -> pooled (LDS only) -> T12 ----------------
__global__ __launch_bounds__(256) void pooled_t12_kernel(
        const float* __restrict__ hidpart, const float* __restrict__ esumpart,
        const float* __restrict__ gW2, const float* __restrict__ gb2,
        const float* __restrict__ lW1, float* __restrict__ T12) {
    __shared__ float hs[128];
    __shared__ float qacc[4][64];
    __shared__ float pb[64];
    __shared__ float esv;
    const int b = blockIdx.x, tid = threadIdx.x;
    if (tid < 128) {
        float s = 0.f;
        for (int sl = 0; sl < NS; ++sl) s += hidpart[(long)sl * (BB * 128) + b * 128 + tid];
        hs[tid] = s;
    } else if (tid == 128) {
        float s = 0.f;
        for (int sl = 0; sl < NS; ++sl) s += esumpart[sl * BB + b];
        esv = s;
    }
    __syncthreads();
    {
        int col = tid & 63, qr = tid >> 6;
        float a = 0.f;
        for (int k = qr * 32; k < qr * 32 + 32; ++k) a += hs[k] * gW2[k * 64 + col];
        qacc[qr][col] = a;
    }
    __syncthreads();
    if (tid < 64) pb[tid] = qacc[0][tid] + qacc[1][tid] + qacc[2][tid] + qacc[3][tid] + esv * gb2[tid];
    __syncthreads();
    const float* col = (tid < 128) ? (lW1 + 64 * 128 + tid) : (lW1 + 192 * 128 + (tid - 128));
    float acc = 0.f;
    for (int k = 0; k < 64; ++k) acc += pb[k] * col[k * 128];
    T12[b * 256 + tid] = acc;
}

// ---------------- local edge pass: src-range partitioned, node-flush on delta change ----------------
__global__ __launch_bounds__(256) void local_edge(
        const ushort* __restrict__ PQL, const int* __restrict__ csr,
        const int* __restrict__ roffs4, const float* __restrict__ lW2,
        const float* __restrict__ lb2, float* __restrict__ out) {
    const int tid = threadIdx.x, w = tid >> 6, l = tid & 63;
    const int rr = (blockIdx.x & 7) >> 1;
    const int g  = (blockIdx.x >> 3) * 2 + (blockIdx.x & 1);
    const int n0 = __builtin_amdgcn_readfirstlane(g * 64 + w * 16);
    const float w20 = lW2[2 * l], w21 = lW2[2 * l + 1];
    const float b2v = lb2[0];

    int i = roffs4[rr * NN + n0];
    const int iend = roffs4[rr * NN + n0 + 16];

    float dacc = 0.f, p0 = 0.f, p1 = 0.f;
    int curD = -1, ecnt = 0;

    for (; i + 8 <= iend; i += 8) {
        int vv[8]; unsigned int qv[8];
#pragma unroll
        for (int k = 0; k < 8; ++k) vv[k] = csr[i + k];
#pragma unroll
        for (int k = 0; k < 8; ++k) {
            const int s = vv[k] & 0x1FFFF;
            qv[k] = *reinterpret_cast<const unsigned int*>(PQL + (long)s * 256 + 128 + 2 * l);
        }
#pragma unroll
        for (int k = 0; k < 8; ++k) {
            const int D = vv[k] >> 17;
            if (D != curD) {
                if (curD >= 0) {
                    float r = dacc;
                    r += __shfl_xor(r, 1, 64);  r += __shfl_xor(r, 2, 64);
                    r += __shfl_xor(r, 4, 64);  r += __shfl_xor(r, 8, 64);
                    r += __shfl_xor(r, 16, 64); r += __shfl_xor(r, 32, 64);
                    if (l == 0) atomicAdd(&out[n0 + curD], r + (float)ecnt * b2v);
                }
                dacc = 0.f; ecnt = 0;
                const unsigned int pdu = *reinterpret_cast<const unsigned int*>(PQL + (long)(n0 + D) * 256 + 2 * l);
                p0 = blo(pdu); p1 = bhi(pdu);
                curD = D;
            }
            dacc += fmaxf(p0 + blo(qv[k]), 0.f) * w20 + fmaxf(p1 + bhi(qv[k]), 0.f) * w21;
            ecnt++;
        }
    }
    for (; i < iend; ++i) {
        const int v = csr[i];
        const int s = v & 0x1FFFF;
        const unsigned int q = *reinterpret_cast<const unsigned int*>(PQL + (long)s * 256 + 128 + 2 * l);
        const int D = v >> 17;
        if (D != curD) {
            if (curD >= 0) {
                float r = dacc;
                r += __shfl_xor(r, 1, 64);  r += __shfl_xor(r, 2, 64);
                r += __shfl_xor(r, 4, 64);  r += __shfl_xor(r, 8, 64);
                r += __shfl_xor(r, 16, 64); r += __shfl_xor(r, 32, 64);
                if (l == 0) atomicAdd(&out[n0 + curD], r + (float)ecnt * b2v);
            }
            dacc = 0.f; ecnt = 0;
            const unsigned int pdu = *reinterpret_cast<const unsigned int*>(PQL + (long)(n0 + D) * 256 + 2 * l);
            p0 = blo(pdu); p1 = bhi(pdu);
            curD = D;
        }
        dacc += fmaxf(p0 + blo(q), 0.f) * w20 + fmaxf(p1 + bhi(q), 0.f) * w21;
        ecnt++;
    }
    if (curD >= 0) {
        float r = dacc;
        r += __shfl_xor(r, 1, 64);  r += __shfl_xor(r, 2, 64);
        r += __shfl_xor(r, 4, 64);  r += __shfl_xor(r, 8, 64);
        r += __shfl_xor(r, 16, 64); r += __shfl_xor(r, 32, 64);
        if (l == 0) atomicAdd(&out[n0 + curD], r + (float)ecnt * b2v);
    }
}

extern "C" void kernel_launch(void* const* d_in, const int* in_sizes, int n_in,
                              void* d_out, int out_size, void* d_ws, size_t ws_size,
                              hipStream_t stream) {
    const float* x   = (const float*)d_in[0];
    const float* e   = (const float*)d_in[1];
    const int*   ei  = (const int*)d_in[2];
    const int*   bat = (const int*)d_in[3];
    const float* gW1 = (const float*)d_in[4];
    const float* gb1 = (const float*)d_in[5];
    const float* gW2 = (const float*)d_in[6];
    const float* gb2 = (const float*)d_in[7];
    const float* lW1 = (const float*)d_in[8];
    const float* lb1 = (const float*)d_in[9];
    const float* lW2 = (const float*)d_in[10];
    const float* lb2 = (const float*)d_in[11];

    char* ws = (char*)d_ws;
    ushort* W1p     = (ushort*)(ws);                     //    32768
    ushort* L1p     = (ushort*)(ws + 32768);             //    32768
    float*  T12     = (float*)(ws + 65536);              //    65536
    float*  esumpart= (float*)(ws + 131072);             //     8192
    float*  hidpart = (float*)(ws + 139264);             //  1048576
    int*    roffs4  = (int*)(ws + 1187840);              //   819204 (4*NN+1 ints)
    int*    bcnt    = (int*)(ws + 2007044);              //    32768
    int*    cnt4    = (int*)(ws + 2039812);              //     8192
    int*    base4   = (int*)(ws + 2048004);              //     8192
    int*    csr     = (int*)(ws + 2056196);              //  3276800
    ushort* PQ      = (ushort*)(ws + 5333008);           // 26214400 (btmp overlays; reused for PQL)
    int2*   btmp    = (int2*)PQ;                         // 16.8 MB, consumed before pq_gemm

    hipMemsetAsync(bcnt, 0, 32768 + 8192, stream);                  // bcnt + cnt4
    hipMemsetAsync(esumpart, 0, 8192 + 1048576, stream);            // esumpart + hidpart
    hipMemsetAsync(d_out, 0, (size_t)out_size * sizeof(float), stream);

    prep_weights<<<1, 512, 0, stream>>>(gW1, lW1, W1p, L1p);
    bucketA_kernel<<<EE / EPB, 512, 0, stream>>>(ei, bcnt, cnt4, btmp);
    scan2048_kernel<<<1, 512, 0, stream>>>(cnt4, base4, roffs4);
    bucketB_kernel<<<NBUCK, 256, 0, stream>>>(btmp, bcnt, base4, roffs4, csr);

    pq_gemm<<<NN / 128, 512, 0, stream>>>(x, W1p, gb1, nullptr, bat, PQ);
    global_edge<<<(NN / 64) * R4, 256, 0, stream>>>(PQ, csr, roffs4, e, bat, hidpart, esumpart);
    pooled_t12_kernel<<<BB, 256, 0, stream>>>(hidpart, esumpart, gW2, gb2, lW1, T12);
    pq_gemm<<<NN / 128, 512, 0, stream>>>(x, L1p, lb1, T12, bat, PQ);   // -> PQL
    local_edge<<<(NN / 64) * R4, 256, 0, stream>>>(PQ, csr, roffs4, lW2, lb2, (float*)d_out);
}